// Round 2
// baseline (97.539 us; speedup 1.0000x reference)
//
#include <hip/hip_runtime.h>
#include <math.h>

// Problem constants (from the JAX reference)
#define IMG    14
#define HW     196       // 14*14 spatial positions
#define DEPTH  512       // channels C
#define NB     512       // batch
#define QS     49        // spatial positions per wave-segment (196 / 4)
#define NSEG   4
#define CTILE  256       // channels per block (64 float4 groups, one per lane)

typedef float f32x4 __attribute__((ext_vector_type(4)));

// Block: 256 threads = 4 waves. Wave q owns spatial positions [q*49, q*49+49).
// Lane g owns a float4 channel group (4 consecutive channels) -> a wave's load
// is 64 lanes x 16B = 1024B contiguous. Grid: 512 b x 2 ctiles = 1024 blocks.
__global__ __launch_bounds__(256) void mask_kernel(const float* __restrict__ x,
                                                   float* __restrict__ out) {
    const int tid = threadIdx.x;
    const int g   = tid & 63;     // float4 channel group within tile
    const int q   = tid >> 6;     // spatial segment (== wave id)
    const int b   = blockIdx.x >> 1;
    const int ct  = blockIdx.x & 1;
    const int c4  = ct * CTILE + (g << 2);   // first channel of this group

    // base float offset of (b, s = q*49, c4)
    const size_t base = ((size_t)b * HW + (size_t)q * QS) * DEPTH + (size_t)c4;
    const float* px = x + base;
    float*       po = out + base;

    // ---- Phase 1: streaming per-component argmax over this segment ----
    float bx = -INFINITY, by = -INFINITY, bz = -INFINITY, bw = -INFINITY;
    int   ix = 0, iy = 0, iz = 0, iw = 0;
#pragma unroll
    for (int k = 0; k < QS; ++k) {
        const f32x4 v = *(const f32x4*)(px + (size_t)k * DEPTH);
        const int s = q * QS + k;
        if (v.x > bx) { bx = v.x; ix = s; }
        if (v.y > by) { by = v.y; iy = s; }
        if (v.z > bz) { bz = v.z; iz = s; }
        if (v.w > bw) { bw = v.w; iw = s; }
    }

    // ---- Cross-segment reduction via LDS (8 KB) ----
    __shared__ f32x4 smax[NSEG][64];
    __shared__ int   sidx[NSEG][64][4];
    f32x4 bv; bv.x = bx; bv.y = by; bv.z = bz; bv.w = bw;
    smax[q][g] = bv;
    sidx[q][g][0] = ix; sidx[q][g][1] = iy; sidx[q][g][2] = iz; sidx[q][g][3] = iw;
    __syncthreads();

    f32x4 m = smax[0][g];
    int mix = sidx[0][g][0], miy = sidx[0][g][1], miz = sidx[0][g][2], miw = sidx[0][g][3];
#pragma unroll
    for (int r = 1; r < NSEG; ++r) {
        // segments scanned in increasing spatial order; strict > keeps the
        // first occurrence, matching jnp.argmax tie semantics
        const f32x4 vv = smax[r][g];
        if (vv.x > m.x) { m.x = vv.x; mix = sidx[r][g][0]; }
        if (vv.y > m.y) { m.y = vv.y; miy = sidx[r][g][1]; }
        if (vv.z > m.z) { m.z = vv.z; miz = sidx[r][g][2]; }
        if (vv.w > m.w) { m.w = vv.w; miw = sidx[r][g][3]; }
    }

    // per-component peak coordinates as floats
    const float fix = (float)(mix / IMG), fjx = (float)(mix % IMG);
    const float fiy = (float)(miy / IMG), fjy = (float)(miy % IMG);
    const float fiz = (float)(miz / IMG), fjz = (float)(miz % IMG);
    const float fiw = (float)(miw / IMG), fjw = (float)(miw % IMG);
    const float TAU = (float)(0.5 / 196.0);

    // ---- Phase 2: re-read (L2/L3-resident), mask, nontemporal store ----
    int si = (q * QS) / IMG;
    int sj = (q * QS) % IMG;
#pragma unroll
    for (int k = 0; k < QS; ++k) {
        const f32x4 v = *(const f32x4*)(px + (size_t)k * DEPTH);
        const float fsi = (float)si;
        const float fsj = (float)sj;
        f32x4 o;
        {
            const float dist = fabsf(fsi - fix) + fabsf(fsj - fjx);
            o.x = v.x * (TAU * fmaxf(1.0f - (4.0f * dist) / 14.0f, -1.0f));
        }
        {
            const float dist = fabsf(fsi - fiy) + fabsf(fsj - fjy);
            o.y = v.y * (TAU * fmaxf(1.0f - (4.0f * dist) / 14.0f, -1.0f));
        }
        {
            const float dist = fabsf(fsi - fiz) + fabsf(fsj - fjz);
            o.z = v.z * (TAU * fmaxf(1.0f - (4.0f * dist) / 14.0f, -1.0f));
        }
        {
            const float dist = fabsf(fsi - fiw) + fabsf(fsj - fjw);
            o.w = v.w * (TAU * fmaxf(1.0f - (4.0f * dist) / 14.0f, -1.0f));
        }
        __builtin_nontemporal_store(o, (f32x4*)(po + (size_t)k * DEPTH));
        // incremental (i,j) walk: s -> s+1
        ++sj;
        if (sj == IMG) { sj = 0; ++si; }
    }
}

extern "C" void kernel_launch(void* const* d_in, const int* in_sizes, int n_in,
                              void* d_out, int out_size, void* d_ws, size_t ws_size,
                              hipStream_t stream) {
    (void)in_sizes; (void)n_in; (void)out_size; (void)d_ws; (void)ws_size;
    const float* x = (const float*)d_in[0];
    float* out = (float*)d_out;
    dim3 grid(NB * (DEPTH / CTILE));  // 1024
    dim3 block(256);
    hipLaunchKernelGGL(mask_kernel, grid, block, 0, stream, x, out);
}

// Round 3
// 83.346 us; speedup vs baseline: 1.1703x; 1.1703x over previous
//
#include <hip/hip_runtime.h>
#include <math.h>

// Problem constants (from the JAX reference)
#define IMG    14
#define HW     196       // 14*14 spatial positions
#define DEPTH  512       // channels C
#define NB     512       // batch
#define NSEG   7         // waves per block = spatial segments
#define PS     28        // spatial positions per wave (196 / 7)
#define CTILE  128       // channels per block (64 lanes x f32x2)

typedef float f32x2 __attribute__((ext_vector_type(2)));

// Block: 448 threads = 7 waves. Wave q owns spatial positions [q*28, q*28+28).
// Lane owns a contiguous f32x2 channel pair -> one wave-load = 64 x 8B = 512B
// contiguous (global_load_dwordx2). Grid: 512 b x 4 ctiles = 2048 blocks.
__global__ __launch_bounds__(448) void mask_kernel(const float* __restrict__ x,
                                                   float* __restrict__ out) {
    const int tid  = threadIdx.x;
    const int lane = tid & 63;
    const int q    = tid >> 6;          // 0..6, spatial segment == wave id
    const int b    = blockIdx.x >> 2;
    const int ct   = blockIdx.x & 3;
    const int c0   = ct * CTILE + (lane << 1);   // first of this lane's 2 channels

    // base float offset of (b, s = q*28, c0)
    const size_t base = ((size_t)b * HW + (size_t)q * PS) * DEPTH + (size_t)c0;
    const float* px = x + base;
    float*       po = out + base;

    // ---- Phase 1: load 28 f32x2 into registers (56 VGPRs, all in flight) ----
    f32x2 v[PS];
#pragma unroll
    for (int k = 0; k < PS; ++k) {
        v[k] = *(const f32x2*)(px + (size_t)k * DEPTH);
    }

    // per-component streaming argmax (first occurrence: strict >)
    float b0 = -INFINITY, b1 = -INFINITY;
    int   i0 = 0, i1 = 0;
#pragma unroll
    for (int k = 0; k < PS; ++k) {
        const int s = q * PS + k;
        if (v[k].x > b0) { b0 = v[k].x; i0 = s; }
        if (v[k].y > b1) { b1 = v[k].y; i1 = s; }
    }

    // ---- Pin loaded values in registers: make them opaque so the compiler
    // cannot rematerialize the global loads in the store phase ----
#pragma unroll
    for (int k = 0; k < PS; ++k) {
        float a = v[k].x, c = v[k].y;
        asm volatile("" : "+v"(a), "+v"(c));
        v[k].x = a; v[k].y = c;
    }

    // ---- Cross-segment reduction via LDS ----
    __shared__ f32x2 smax[NSEG][64];
    __shared__ int   sidx[NSEG][64][2];
    f32x2 bv; bv.x = b0; bv.y = b1;
    smax[q][lane] = bv;
    sidx[q][lane][0] = i0; sidx[q][lane][1] = i1;
    __syncthreads();

    f32x2 m = smax[0][lane];
    int mi0 = sidx[0][lane][0], mi1 = sidx[0][lane][1];
#pragma unroll
    for (int r = 1; r < NSEG; ++r) {
        // segments scanned in increasing spatial order; strict > keeps the
        // first occurrence, matching jnp.argmax tie semantics
        const f32x2 vv = smax[r][lane];
        if (vv.x > m.x) { m.x = vv.x; mi0 = sidx[r][lane][0]; }
        if (vv.y > m.y) { m.y = vv.y; mi1 = sidx[r][lane][1]; }
    }

    const float fi0 = (float)(mi0 / IMG), fj0 = (float)(mi0 % IMG);
    const float fi1 = (float)(mi1 / IMG), fj1 = (float)(mi1 % IMG);
    const float TAU = (float)(0.5 / 196.0);

    // ---- Phase 2: mask register-held values, store (no global re-read) ----
    int si = (q * PS) / IMG;
    int sj = (q * PS) % IMG;
#pragma unroll
    for (int k = 0; k < PS; ++k) {
        const float fsi = (float)si;
        const float fsj = (float)sj;
        f32x2 o;
        {
            const float dist = fabsf(fsi - fi0) + fabsf(fsj - fj0);
            o.x = v[k].x * (TAU * fmaxf(1.0f - (4.0f * dist) / 14.0f, -1.0f));
        }
        {
            const float dist = fabsf(fsi - fi1) + fabsf(fsj - fj1);
            o.y = v[k].y * (TAU * fmaxf(1.0f - (4.0f * dist) / 14.0f, -1.0f));
        }
        *(f32x2*)(po + (size_t)k * DEPTH) = o;
        ++sj;
        if (sj == IMG) { sj = 0; ++si; }
    }
}

extern "C" void kernel_launch(void* const* d_in, const int* in_sizes, int n_in,
                              void* d_out, int out_size, void* d_ws, size_t ws_size,
                              hipStream_t stream) {
    (void)in_sizes; (void)n_in; (void)out_size; (void)d_ws; (void)ws_size;
    const float* x = (const float*)d_in[0];
    float* out = (float*)d_out;
    dim3 grid(NB * (DEPTH / CTILE));  // 2048
    dim3 block(448);
    hipLaunchKernelGGL(mask_kernel, grid, block, 0, stream, x, out);
}